// Round 1
// baseline (1949.107 us; speedup 1.0000x reference)
//
#include <hip/hip_runtime.h>
#include <math.h>

#define BN 64
#define PN 16800
#define ON 64
#define THRESH 0.35f
#define NEGPOS 7

// ---------- monotone float<->uint key (orderable as unsigned) ----------
__device__ __forceinline__ unsigned f2key(float f) {
  unsigned u = __float_as_uint(f);
  return (u & 0x80000000u) ? ~u : (u | 0x80000000u);
}
__device__ __forceinline__ float key2f(unsigned k) {
  unsigned u = (k & 0x80000000u) ? (k & 0x7FFFFFFFu) : ~k;
  return __uint_as_float(u);
}

struct Acc {
  unsigned xmax_key;      // global max of conf_data (encoded)
  int npos[BN];           // per-row positive count
  int nposlm_tot;         // total pos1 count (landm)
  float sum_l;            // smooth-l1 loc sum
  float sum_lm;           // smooth-l1 landm sum
  float sum_c;            // selected CE sum
  unsigned Tkey[BN];      // per-row k-th largest loss_c key
  unsigned Rsel[BN];      // per-row number of tie elements to include
};

__device__ __forceinline__ float sl1(float d) {
  float a = fabsf(d);
  return (a < 1.f) ? 0.5f * a * a : a - 0.5f;
}

// ---------- K_init: zero the accumulator block ----------
__global__ void k_init(Acc* acc) {
  int n = (int)(sizeof(Acc) / 4);
  int* p = (int*)acc;
  for (int i = threadIdx.x; i < n; i += blockDim.x) p[i] = 0;
}

// ---------- K0: global max of conf_data ----------
__global__ void k_max(const float* __restrict__ conf, Acc* acc) {
  int stride = gridDim.x * blockDim.x;
  float m = -INFINITY;
  for (int i = blockIdx.x * blockDim.x + threadIdx.x; i < BN * PN * 2; i += stride)
    m = fmaxf(m, conf[i]);
  for (int off = 32; off; off >>= 1) m = fmaxf(m, __shfl_down(m, off));
  if ((threadIdx.x & 63) == 0) atomicMax(&acc->xmax_key, f2key(m));
}

// ---------- K1: per-prior best truth (max over axis 0, first argmax) ----------
__global__ void k_best_truth(const float* __restrict__ priors,
                             const float* __restrict__ targets,
                             float* __restrict__ bto, int* __restrict__ bti) {
  int b = blockIdx.y;
  int p = blockIdx.x * 256 + threadIdx.x;
  __shared__ float tb[ON][4];
  if (threadIdx.x < ON * 4) {
    int t = threadIdx.x >> 2, j = threadIdx.x & 3;
    tb[t][j] = targets[(b * ON + t) * 15 + j];
  }
  __syncthreads();
  if (p >= PN) return;
  float4 pr = reinterpret_cast<const float4*>(priors)[p];
  float px1 = pr.x - pr.z * 0.5f, py1 = pr.y - pr.w * 0.5f;
  float px2 = pr.x + pr.z * 0.5f, py2 = pr.y + pr.w * 0.5f;
  float area_b = (px2 - px1) * (py2 - py1);
  float best = -1.f; int bidx = 0;
  for (int t = 0; t < ON; t++) {
    float ax1 = tb[t][0], ay1 = tb[t][1], ax2 = tb[t][2], ay2 = tb[t][3];
    float lx = fmaxf(ax1, px1), ly = fmaxf(ay1, py1);
    float rx = fminf(ax2, px2), ry = fminf(ay2, py2);
    float w = fmaxf(rx - lx, 0.f), h = fmaxf(ry - ly, 0.f);
    float inter = w * h;
    float area_a = (ax2 - ax1) * (ay2 - ay1);
    float iou = inter / (area_a + area_b - inter);
    if (iou > best) { best = iou; bidx = t; }
  }
  bto[b * PN + p] = best;
  bti[b * PN + p] = bidx;
}

// ---------- K2: per-truth best prior (one wave per (b,t)) ----------
__global__ void k_best_prior(const float* __restrict__ priors,
                             const float* __restrict__ targets,
                             float* __restrict__ bpo, int* __restrict__ bpi) {
  int pair = blockIdx.x * 4 + (threadIdx.x >> 6);
  int lane = threadIdx.x & 63;
  int b = pair >> 6, t = pair & 63;
  const float* tg = &targets[(b * ON + t) * 15];
  float ax1 = tg[0], ay1 = tg[1], ax2 = tg[2], ay2 = tg[3];
  float area_a = (ax2 - ax1) * (ay2 - ay1);
  float best = -1.f; int bidx = 0x7FFFFFFF;
  for (int p = lane; p < PN; p += 64) {
    float4 pr = reinterpret_cast<const float4*>(priors)[p];
    float px1 = pr.x - pr.z * 0.5f, py1 = pr.y - pr.w * 0.5f;
    float px2 = pr.x + pr.z * 0.5f, py2 = pr.y + pr.w * 0.5f;
    float lx = fmaxf(ax1, px1), ly = fmaxf(ay1, py1);
    float rx = fminf(ax2, px2), ry = fminf(ay2, py2);
    float w = fmaxf(rx - lx, 0.f), h = fmaxf(ry - ly, 0.f);
    float inter = w * h;
    float area_b = (px2 - px1) * (py2 - py1);
    float iou = inter / (area_a + area_b - inter);
    if (iou > best) { best = iou; bidx = p; }
  }
  // butterfly reduce: larger overlap wins; tie -> smaller index (first occurrence)
  for (int off = 1; off < 64; off <<= 1) {
    float ov2 = __shfl_xor(best, off);
    int i2 = __shfl_xor(bidx, off);
    if (ov2 > best || (ov2 == best && i2 < bidx)) { best = ov2; bidx = i2; }
  }
  if (lane == 0) { bpo[b * ON + t] = best; bpi[b * ON + t] = bidx; }
}

// ---------- K3: sequential scatter fixups (numpy last-write-wins) ----------
__global__ void k_scatter(const float* __restrict__ bpo, const int* __restrict__ bpi,
                          float* __restrict__ bto, int* __restrict__ bti) {
  int b = threadIdx.x;
  if (b >= BN) return;
  int idxs[ON];
  float orig[ON];
  for (int t = 0; t < ON; t++) idxs[t] = bpi[b * ON + t];
  for (int t = 0; t < ON; t++) orig[t] = bto[b * PN + idxs[t]];  // pre-update gather
  for (int t = 0; t < ON; t++) {
    bool valid = bpo[b * ON + t] >= 0.2f;
    bto[b * PN + idxs[t]] = valid ? 2.0f : orig[t];
    bti[b * PN + idxs[t]] = t;  // unconditional in reference
  }
}

// ---------- K4: encode + smooth-l1 sums + loss_c + pos flags + counts ----------
__global__ void k_encode(const float* __restrict__ loc_data,
                         const float* __restrict__ conf_data,
                         const float* __restrict__ landm_data,
                         const float* __restrict__ priors,
                         const float* __restrict__ targets,
                         const float* __restrict__ bto, const int* __restrict__ bti,
                         float* __restrict__ lossc, unsigned char* __restrict__ posf,
                         Acc* acc) {
  int b = blockIdx.y;
  int p = blockIdx.x * 256 + threadIdx.x;
  float sum_l = 0.f, sum_lm = 0.f;
  int cp = 0, cp1 = 0;
  if (p < PN) {
    int t = bti[b * PN + p];
    float ov = bto[b * PN + p];
    const float* tg = &targets[(b * ON + t) * 15];
    float label = tg[14];
    float conf = (ov < THRESH) ? 0.f : label;
    bool pos = (conf != 0.f);
    bool pos1 = (conf > 0.f);
    float4 pr = reinterpret_cast<const float4*>(priors)[p];
    float ivx = 1.f / (0.1f * pr.z), ivy = 1.f / (0.1f * pr.w);
    if (pos) {
      float m0 = tg[0], m1 = tg[1], m2 = tg[2], m3 = tg[3];
      float g0 = ((m0 + m2) * 0.5f - pr.x) / (0.1f * pr.z);
      float g1 = ((m1 + m3) * 0.5f - pr.y) / (0.1f * pr.w);
      float g2 = logf((m2 - m0) / pr.z) / 0.2f;
      float g3 = logf((m3 - m1) / pr.w) / 0.2f;
      const float* ld = &loc_data[((long)b * PN + p) * 4];
      sum_l = sl1(ld[0] - g0) + sl1(ld[1] - g1) + sl1(ld[2] - g2) + sl1(ld[3] - g3);
      cp = 1;
    }
    if (pos1) {
      const float* lm = &landm_data[((long)b * PN + p) * 10];
      for (int i = 0; i < 5; i++) {
        float gx = (tg[4 + 2 * i] - pr.x) / (0.1f * pr.z);
        float gy = (tg[5 + 2 * i] - pr.y) / (0.1f * pr.w);
        sum_lm += sl1(lm[2 * i] - gx) + sl1(lm[2 * i + 1] - gy);
      }
      cp1 = 1;
    }
    (void)ivx; (void)ivy;
    float x0 = conf_data[((long)b * PN + p) * 2];
    float x1 = conf_data[((long)b * PN + p) * 2 + 1];
    float xmax = key2f(acc->xmax_key);
    float lse = logf(expf(x0 - xmax) + expf(x1 - xmax)) + xmax;
    lossc[b * PN + p] = lse - (pos ? x1 : x0);
    posf[b * PN + p] = pos ? 1 : 0;
  }
  // wave-level reduce, one atomic set per wave
  for (int off = 32; off; off >>= 1) {
    sum_l += __shfl_down(sum_l, off);
    sum_lm += __shfl_down(sum_lm, off);
    cp += __shfl_down(cp, off);
    cp1 += __shfl_down(cp1, off);
  }
  if ((threadIdx.x & 63) == 0) {
    if (sum_l != 0.f) atomicAdd(&acc->sum_l, sum_l);
    if (sum_lm != 0.f) atomicAdd(&acc->sum_lm, sum_lm);
    if (cp) atomicAdd(&acc->npos[b], cp);
    if (cp1) atomicAdd(&acc->nposlm_tot, cp1);
  }
}

// ---------- K5: per-row radix select of k-th largest loss_c ----------
__global__ void k_select(const float* __restrict__ lossc, Acc* acc) {
  int b = blockIdx.x;
  __shared__ unsigned hist[256];
  __shared__ unsigned s_chosen, s_rem;
  int np = acc->npos[b];
  long k = (long)NEGPOS * np;
  if (k > PN - 1) k = PN - 1;
  if (k <= 0) {
    if (threadIdx.x == 0) { acc->Tkey[b] = 0xFFFFFFFFu; acc->Rsel[b] = 0; }
    return;
  }
  unsigned prefix = 0;
  unsigned remaining = (unsigned)k;
  const float* row = &lossc[b * PN];
  for (int pass = 0; pass < 4; pass++) {
    int shift = 24 - pass * 8;
    hist[threadIdx.x] = 0;
    __syncthreads();
    unsigned hmask = (pass == 0) ? 0u : (0xFFFFFFFFu << (shift + 8));
    for (int p = threadIdx.x; p < PN; p += 256) {
      unsigned key = f2key(row[p]);
      if (((key ^ prefix) & hmask) == 0)
        atomicAdd(&hist[(key >> shift) & 255], 1u);
    }
    __syncthreads();
    if (threadIdx.x == 0) {
      unsigned cum = 0;
      for (int d = 255; d >= 0; d--) {
        unsigned c = hist[d];
        if (cum + c >= remaining) { s_chosen = (unsigned)d; s_rem = remaining - cum; break; }
        cum += c;
      }
    }
    __syncthreads();
    prefix |= s_chosen << shift;
    remaining = s_rem;
    __syncthreads();
  }
  if (threadIdx.x == 0) { acc->Tkey[b] = prefix; acc->Rsel[b] = remaining; }
}

// ---------- K6: accumulate CE over pos | neg ----------
__global__ void k_conf_sum(const float* __restrict__ conf_data,
                           const float* __restrict__ lossc,
                           const unsigned char* __restrict__ posf,
                           Acc* acc) {
  int b = blockIdx.y;
  int p = blockIdx.x * 256 + threadIdx.x;
  float s = 0.f;
  if (p < PN) {
    unsigned T = acc->Tkey[b];
    unsigned R = acc->Rsel[b];
    unsigned key = f2key(lossc[b * PN + p]);
    bool pos = posf[b * PN + p] != 0;
    bool neg = key > T;
    if (!neg && key == T && R > 0) {
      // rare tie path: count equal keys with smaller index (stable-sort tiebreak)
      unsigned cnt = 0;
      const float* row = &lossc[b * PN];
      for (int j = 0; j < p; j++) cnt += (f2key(row[j]) == T) ? 1u : 0u;
      neg = cnt < R;
    }
    if (pos || neg) {
      float x0 = conf_data[((long)b * PN + p) * 2];
      float x1 = conf_data[((long)b * PN + p) * 2 + 1];
      float m = fmaxf(x0, x1);
      float lse = m + logf(expf(x0 - m) + expf(x1 - m));
      s = lse - (pos ? x1 : x0);
    }
  }
  for (int off = 32; off; off >>= 1) s += __shfl_down(s, off);
  if ((threadIdx.x & 63) == 0 && s != 0.f) atomicAdd(&acc->sum_c, s);
}

// ---------- K7: finalize three scalars ----------
__global__ void k_final(const Acc* __restrict__ acc, float* __restrict__ out) {
  if (threadIdx.x == 0) {
    int npt = 0;
    for (int b = 0; b < BN; b++) npt += acc->npos[b];
    float N = fmaxf((float)npt, 1.f);
    float N1 = fmaxf((float)acc->nposlm_tot, 1.f);
    out[0] = acc->sum_l / N;
    out[1] = acc->sum_c / N;
    out[2] = acc->sum_lm / N1;
  }
}

extern "C" void kernel_launch(void* const* d_in, const int* in_sizes, int n_in,
                              void* d_out, int out_size, void* d_ws, size_t ws_size,
                              hipStream_t stream) {
  const float* loc_data = (const float*)d_in[0];
  const float* conf_data = (const float*)d_in[1];
  const float* landm_data = (const float*)d_in[2];
  const float* priors = (const float*)d_in[3];
  const float* targets = (const float*)d_in[4];
  float* out = (float*)d_out;

  char* ws = (char*)d_ws;
  const size_t SZ = (size_t)BN * PN * 4;  // 4.3 MB per float array
  float* lossc = (float*)(ws);
  float* bto = (float*)(ws + SZ);
  int* bti = (int*)(ws + 2 * SZ);
  unsigned char* posf = (unsigned char*)(ws + 3 * SZ);
  float* bpo = (float*)(ws + 3 * SZ + (size_t)BN * PN);
  int* bpi = (int*)(ws + 3 * SZ + (size_t)BN * PN + (size_t)BN * ON * 4);
  Acc* acc = (Acc*)(ws + 3 * SZ + (size_t)BN * PN + (size_t)BN * ON * 8);

  dim3 gbp((PN + 255) / 256, BN);

  k_init<<<1, 256, 0, stream>>>(acc);
  k_max<<<512, 256, 0, stream>>>(conf_data, acc);
  k_best_truth<<<gbp, 256, 0, stream>>>(priors, targets, bto, bti);
  k_best_prior<<<(BN * ON) / 4, 256, 0, stream>>>(priors, targets, bpo, bpi);
  k_scatter<<<1, 64, 0, stream>>>(bpo, bpi, bto, bti);
  k_encode<<<gbp, 256, 0, stream>>>(loc_data, conf_data, landm_data, priors, targets,
                                    bto, bti, lossc, posf, acc);
  k_select<<<BN, 256, 0, stream>>>(lossc, acc);
  k_conf_sum<<<gbp, 256, 0, stream>>>(conf_data, lossc, posf, acc);
  k_final<<<1, 64, 0, stream>>>(acc, out);
}

// Round 2
// 372.584 us; speedup vs baseline: 5.2313x; 5.2313x over previous
//
#include <hip/hip_runtime.h>
#include <math.h>

#define BN 64
#define PN 16800
#define ON 64
#define THRESH 0.35f
#define NEGPOS 7
#define GX 66                 // blocks per row in p-dim (66*256 >= 16800)
#define NBLK (BN * GX)        // 4224 partial slots
#define NBMAX 128             // k_max grid

// ---------- monotone float<->uint key (orderable as unsigned) ----------
__device__ __forceinline__ unsigned f2key(float f) {
  unsigned u = __float_as_uint(f);
  return (u & 0x80000000u) ? ~u : (u | 0x80000000u);
}
__device__ __forceinline__ float key2f(unsigned k) {
  unsigned u = (k & 0x80000000u) ? (k & 0x7FFFFFFFu) : ~k;
  return __uint_as_float(u);
}

struct Acc {
  unsigned xmax_key;   // global max of conf_data (encoded key)
  unsigned Tkey[BN];   // per-row k-th largest loss_c key
  unsigned Rsel[BN];   // per-row number of tie elements to include
  unsigned Ctie[BN];   // per-row total count of elements equal to Tkey
};

__device__ __forceinline__ float sl1(float d) {
  float a = fabsf(d);
  return (a < 1.f) ? 0.5f * a * a : a - 0.5f;
}

// ---------- K0: per-block max of conf_data (no atomics) ----------
__global__ void k_max(const float* __restrict__ conf, unsigned* __restrict__ bmax) {
  int stride = gridDim.x * blockDim.x;
  float m = -INFINITY;
  for (int i = blockIdx.x * blockDim.x + threadIdx.x; i < BN * PN * 2; i += stride)
    m = fmaxf(m, conf[i]);
  for (int off = 32; off; off >>= 1) m = fmaxf(m, __shfl_down(m, off));
  __shared__ float wmax[4];
  if ((threadIdx.x & 63) == 0) wmax[threadIdx.x >> 6] = m;
  __syncthreads();
  if (threadIdx.x == 0) {
    float mm = fmaxf(fmaxf(wmax[0], wmax[1]), fmaxf(wmax[2], wmax[3]));
    bmax[blockIdx.x] = f2key(mm);
  }
}

// ---------- K1: per-prior best truth (max over axis 0, first argmax) ----------
__global__ void k_best_truth(const float* __restrict__ priors,
                             const float* __restrict__ targets,
                             float* __restrict__ bto, int* __restrict__ bti) {
  int b = blockIdx.y;
  int p = blockIdx.x * 256 + threadIdx.x;
  __shared__ float tb[ON][4];
  if (threadIdx.x < ON * 4) {
    int t = threadIdx.x >> 2, j = threadIdx.x & 3;
    tb[t][j] = targets[(b * ON + t) * 15 + j];
  }
  __syncthreads();
  if (p >= PN) return;
  float4 pr = reinterpret_cast<const float4*>(priors)[p];
  float px1 = pr.x - pr.z * 0.5f, py1 = pr.y - pr.w * 0.5f;
  float px2 = pr.x + pr.z * 0.5f, py2 = pr.y + pr.w * 0.5f;
  float area_b = (px2 - px1) * (py2 - py1);
  float best = -1.f; int bidx = 0;
  for (int t = 0; t < ON; t++) {
    float ax1 = tb[t][0], ay1 = tb[t][1], ax2 = tb[t][2], ay2 = tb[t][3];
    float lx = fmaxf(ax1, px1), ly = fmaxf(ay1, py1);
    float rx = fminf(ax2, px2), ry = fminf(ay2, py2);
    float w = fmaxf(rx - lx, 0.f), h = fmaxf(ry - ly, 0.f);
    float inter = w * h;
    float area_a = (ax2 - ax1) * (ay2 - ay1);
    float iou = inter / (area_a + area_b - inter);
    if (iou > best) { best = iou; bidx = t; }
  }
  bto[b * PN + p] = best;
  bti[b * PN + p] = bidx;
}

// ---------- K2: per-truth best prior (one wave per (b,t)) ----------
__global__ void k_best_prior(const float* __restrict__ priors,
                             const float* __restrict__ targets,
                             float* __restrict__ bpo, int* __restrict__ bpi) {
  int pair = blockIdx.x * 4 + (threadIdx.x >> 6);
  int lane = threadIdx.x & 63;
  int b = pair >> 6, t = pair & 63;
  const float* tg = &targets[(b * ON + t) * 15];
  float ax1 = tg[0], ay1 = tg[1], ax2 = tg[2], ay2 = tg[3];
  float area_a = (ax2 - ax1) * (ay2 - ay1);
  float best = -1.f; int bidx = 0x7FFFFFFF;
  for (int p = lane; p < PN; p += 64) {
    float4 pr = reinterpret_cast<const float4*>(priors)[p];
    float px1 = pr.x - pr.z * 0.5f, py1 = pr.y - pr.w * 0.5f;
    float px2 = pr.x + pr.z * 0.5f, py2 = pr.y + pr.w * 0.5f;
    float lx = fmaxf(ax1, px1), ly = fmaxf(ay1, py1);
    float rx = fminf(ax2, px2), ry = fminf(ay2, py2);
    float w = fmaxf(rx - lx, 0.f), h = fmaxf(ry - ly, 0.f);
    float inter = w * h;
    float area_b = (px2 - px1) * (py2 - py1);
    float iou = inter / (area_a + area_b - inter);
    if (iou > best) { best = iou; bidx = p; }
  }
  for (int off = 1; off < 64; off <<= 1) {
    float ov2 = __shfl_xor(best, off);
    int i2 = __shfl_xor(bidx, off);
    if (ov2 > best || (ov2 == best && i2 < bidx)) { best = ov2; bidx = i2; }
  }
  if (lane == 0) { bpo[b * ON + t] = best; bpi[b * ON + t] = bidx; }
}

// ---------- K3: sequential scatter fixups + combine global max ----------
__global__ void k_scatter(const unsigned* __restrict__ bmax,
                          const float* __restrict__ bpo, const int* __restrict__ bpi,
                          float* __restrict__ bto, int* __restrict__ bti, Acc* acc) {
  int b = threadIdx.x;  // 64 threads = 1 wave
  // combine 128 block maxes -> acc->xmax_key
  unsigned mk = bmax[b];
  unsigned mk2 = bmax[b + 64];
  if (mk2 > mk) mk = mk2;
  for (int off = 1; off < 64; off <<= 1) {
    unsigned o = (unsigned)__shfl_xor((int)mk, off);
    if (o > mk) mk = o;
  }
  if (b == 0) acc->xmax_key = mk;

  int idxs[ON];
  float orig[ON];
  for (int t = 0; t < ON; t++) idxs[t] = bpi[b * ON + t];
  for (int t = 0; t < ON; t++) orig[t] = bto[b * PN + idxs[t]];  // pre-update gather
  for (int t = 0; t < ON; t++) {
    bool valid = bpo[b * ON + t] >= 0.2f;
    bto[b * PN + idxs[t]] = valid ? 2.0f : orig[t];
    bti[b * PN + idxs[t]] = t;  // unconditional in reference
  }
}

// ---------- K4: encode + smooth-l1 + loss_c + per-block partials ----------
__global__ void k_encode(const float* __restrict__ loc_data,
                         const float* __restrict__ conf_data,
                         const float* __restrict__ landm_data,
                         const float* __restrict__ priors,
                         const float* __restrict__ targets,
                         const float* __restrict__ bto, const int* __restrict__ bti,
                         float* __restrict__ lossc, unsigned char* __restrict__ posf,
                         const Acc* __restrict__ acc,
                         float* __restrict__ part_l, float* __restrict__ part_lm,
                         int* __restrict__ np_part, int* __restrict__ np1_part) {
  int b = blockIdx.y;
  int p = blockIdx.x * 256 + threadIdx.x;
  int bid = b * GX + blockIdx.x;
  float sum_l = 0.f, sum_lm = 0.f;
  int cp = 0, cp1 = 0;
  if (p < PN) {
    int t = bti[b * PN + p];
    float ov = bto[b * PN + p];
    const float* tg = &targets[(b * ON + t) * 15];
    float label = tg[14];
    float conf = (ov < THRESH) ? 0.f : label;
    bool pos = (conf != 0.f);
    bool pos1 = (conf > 0.f);
    float4 pr = reinterpret_cast<const float4*>(priors)[p];
    if (pos) {
      float m0 = tg[0], m1 = tg[1], m2 = tg[2], m3 = tg[3];
      float g0 = ((m0 + m2) * 0.5f - pr.x) / (0.1f * pr.z);
      float g1 = ((m1 + m3) * 0.5f - pr.y) / (0.1f * pr.w);
      float g2 = logf((m2 - m0) / pr.z) / 0.2f;
      float g3 = logf((m3 - m1) / pr.w) / 0.2f;
      const float* ld = &loc_data[((long)b * PN + p) * 4];
      sum_l = sl1(ld[0] - g0) + sl1(ld[1] - g1) + sl1(ld[2] - g2) + sl1(ld[3] - g3);
      cp = 1;
    }
    if (pos1) {
      const float* lm = &landm_data[((long)b * PN + p) * 10];
      for (int i = 0; i < 5; i++) {
        float gx = (tg[4 + 2 * i] - pr.x) / (0.1f * pr.z);
        float gy = (tg[5 + 2 * i] - pr.y) / (0.1f * pr.w);
        sum_lm += sl1(lm[2 * i] - gx) + sl1(lm[2 * i + 1] - gy);
      }
      cp1 = 1;
    }
    float x0 = conf_data[((long)b * PN + p) * 2];
    float x1 = conf_data[((long)b * PN + p) * 2 + 1];
    float xmax = key2f(acc->xmax_key);
    float lse = logf(expf(x0 - xmax) + expf(x1 - xmax)) + xmax;
    lossc[b * PN + p] = lse - (pos ? x1 : x0);
    posf[b * PN + p] = pos ? 1 : 0;
  }
  // block reduce -> one partial store per block (NO global atomics)
  for (int off = 32; off; off >>= 1) {
    sum_l += __shfl_down(sum_l, off);
    sum_lm += __shfl_down(sum_lm, off);
    cp += __shfl_down(cp, off);
    cp1 += __shfl_down(cp1, off);
  }
  __shared__ float sl4[4], slm4[4];
  __shared__ int sp4[4], sp14[4];
  int w = threadIdx.x >> 6;
  if ((threadIdx.x & 63) == 0) { sl4[w] = sum_l; slm4[w] = sum_lm; sp4[w] = cp; sp14[w] = cp1; }
  __syncthreads();
  if (threadIdx.x == 0) {
    part_l[bid] = sl4[0] + sl4[1] + sl4[2] + sl4[3];
    part_lm[bid] = slm4[0] + slm4[1] + slm4[2] + slm4[3];
    np_part[bid] = sp4[0] + sp4[1] + sp4[2] + sp4[3];
    np1_part[bid] = sp14[0] + sp14[1] + sp14[2] + sp14[3];
  }
}

// ---------- K5: per-row radix select of k-th largest loss_c ----------
__global__ void k_select(const float* __restrict__ lossc,
                         const int* __restrict__ np_part, Acc* acc) {
  int b = blockIdx.x;
  int tid = threadIdx.x;
  __shared__ unsigned hist[256];
  __shared__ unsigned suf[256];
  __shared__ unsigned s_chosen, s_rem;
  __shared__ int s_np;
  __shared__ int wnp[4];

  // per-row num_pos = sum of this row's block partials
  int local = 0;
  for (int i = tid; i < GX; i += 256) local += np_part[b * GX + i];
  for (int off = 32; off; off >>= 1) local += __shfl_down(local, off);
  if ((tid & 63) == 0) wnp[tid >> 6] = local;
  __syncthreads();
  if (tid == 0) s_np = wnp[0] + wnp[1] + wnp[2] + wnp[3];
  __syncthreads();
  int np = s_np;
  long k = (long)NEGPOS * np;
  if (k > PN - 1) k = PN - 1;
  if (k <= 0) {
    if (tid == 0) { acc->Tkey[b] = 0xFFFFFFFFu; acc->Rsel[b] = 0; acc->Ctie[b] = 0; }
    return;
  }
  unsigned prefix = 0, remaining = (unsigned)k, lastC = 0;
  const float* row = &lossc[b * PN];
  for (int pass = 0; pass < 4; pass++) {
    int shift = 24 - pass * 8;
    hist[tid] = 0;
    __syncthreads();
    unsigned hmask = (pass == 0) ? 0u : (0xFFFFFFFFu << (shift + 8));
    for (int p = tid; p < PN; p += 256) {
      unsigned key = f2key(row[p]);
      if (((key ^ prefix) & hmask) == 0)
        atomicAdd(&hist[(key >> shift) & 255], 1u);
    }
    __syncthreads();
    // parallel suffix-sum: suf[d] = sum_{d'>=d} hist[d']
    suf[tid] = hist[tid];
    __syncthreads();
    for (int off = 1; off < 256; off <<= 1) {
      unsigned t = (tid + off < 256) ? suf[tid + off] : 0;
      __syncthreads();
      suf[tid] += t;
      __syncthreads();
    }
    unsigned nextS = (tid < 255) ? suf[tid + 1] : 0;
    if (suf[tid] >= remaining && nextS < remaining) {  // unique crossing point
      s_chosen = (unsigned)tid;
      s_rem = remaining - nextS;
    }
    __syncthreads();
    prefix |= s_chosen << shift;
    remaining = s_rem;
    if (pass == 3) lastC = hist[s_chosen];
    __syncthreads();
  }
  if (tid == 0) { acc->Tkey[b] = prefix; acc->Rsel[b] = remaining; acc->Ctie[b] = lastC; }
}

// ---------- K6: accumulate CE over pos|neg -> per-block partials ----------
__global__ void k_conf_sum(const float* __restrict__ conf_data,
                           const float* __restrict__ lossc,
                           const unsigned char* __restrict__ posf,
                           const Acc* __restrict__ acc, float* __restrict__ part_c) {
  int b = blockIdx.y;
  int p = blockIdx.x * 256 + threadIdx.x;
  int bid = b * GX + blockIdx.x;
  float s = 0.f;
  if (p < PN) {
    unsigned T = acc->Tkey[b];
    unsigned R = acc->Rsel[b];
    unsigned C = acc->Ctie[b];
    unsigned key = f2key(lossc[b * PN + p]);
    bool pos = posf[b * PN + p] != 0;
    bool neg = false;
    if (R > 0) {
      neg = key > T;
      if (!neg && key == T) {
        if (C == R) {
          neg = true;  // fast path: all ties selected
        } else {
          // rare: more ties than slots -> first R in index order win
          unsigned cnt = 0;
          const float* row = &lossc[b * PN];
          for (int j = 0; j < p; j++) cnt += (f2key(row[j]) == T) ? 1u : 0u;
          neg = cnt < R;
        }
      }
    }
    if (pos || neg) {
      float x0 = conf_data[((long)b * PN + p) * 2];
      float x1 = conf_data[((long)b * PN + p) * 2 + 1];
      float m = fmaxf(x0, x1);
      float lse = m + logf(expf(x0 - m) + expf(x1 - m));
      s = lse - (pos ? x1 : x0);
    }
  }
  for (int off = 32; off; off >>= 1) s += __shfl_down(s, off);
  __shared__ float sc4[4];
  if ((threadIdx.x & 63) == 0) sc4[threadIdx.x >> 6] = s;
  __syncthreads();
  if (threadIdx.x == 0) part_c[bid] = sc4[0] + sc4[1] + sc4[2] + sc4[3];
}

// ---------- K7: reduce all partials, finalize three scalars ----------
__global__ void k_final(const float* __restrict__ part_l, const float* __restrict__ part_lm,
                        const float* __restrict__ part_c,
                        const int* __restrict__ np_part, const int* __restrict__ np1_part,
                        float* __restrict__ out) {
  float sl = 0.f, slm = 0.f, sc = 0.f;
  int np = 0, np1 = 0;
  for (int i = threadIdx.x; i < NBLK; i += 256) {
    sl += part_l[i]; slm += part_lm[i]; sc += part_c[i];
    np += np_part[i]; np1 += np1_part[i];
  }
  for (int off = 32; off; off >>= 1) {
    sl += __shfl_down(sl, off); slm += __shfl_down(slm, off); sc += __shfl_down(sc, off);
    np += __shfl_down(np, off); np1 += __shfl_down(np1, off);
  }
  __shared__ float a[4], bsh[4], c[4];
  __shared__ int d[4], e[4];
  int w = threadIdx.x >> 6;
  if ((threadIdx.x & 63) == 0) { a[w] = sl; bsh[w] = slm; c[w] = sc; d[w] = np; e[w] = np1; }
  __syncthreads();
  if (threadIdx.x == 0) {
    float N = fmaxf((float)(d[0] + d[1] + d[2] + d[3]), 1.f);
    float N1 = fmaxf((float)(e[0] + e[1] + e[2] + e[3]), 1.f);
    out[0] = (a[0] + a[1] + a[2] + a[3]) / N;
    out[1] = (c[0] + c[1] + c[2] + c[3]) / N;
    out[2] = (bsh[0] + bsh[1] + bsh[2] + bsh[3]) / N1;
  }
}

extern "C" void kernel_launch(void* const* d_in, const int* in_sizes, int n_in,
                              void* d_out, int out_size, void* d_ws, size_t ws_size,
                              hipStream_t stream) {
  const float* loc_data = (const float*)d_in[0];
  const float* conf_data = (const float*)d_in[1];
  const float* landm_data = (const float*)d_in[2];
  const float* priors = (const float*)d_in[3];
  const float* targets = (const float*)d_in[4];
  float* out = (float*)d_out;

  char* ws = (char*)d_ws;
  const size_t SZ = (size_t)BN * PN * 4;  // 4.3 MB per float array
  size_t off = 0;
  float* lossc = (float*)(ws + off); off += SZ;
  float* bto = (float*)(ws + off); off += SZ;
  int* bti = (int*)(ws + off); off += SZ;
  unsigned char* posf = (unsigned char*)(ws + off); off += (size_t)BN * PN;
  off = (off + 15) & ~(size_t)15;
  float* bpo = (float*)(ws + off); off += (size_t)BN * ON * 4;
  int* bpi = (int*)(ws + off); off += (size_t)BN * ON * 4;
  unsigned* bmax = (unsigned*)(ws + off); off += NBMAX * 4;
  float* part_l = (float*)(ws + off); off += NBLK * 4;
  float* part_lm = (float*)(ws + off); off += NBLK * 4;
  float* part_c = (float*)(ws + off); off += NBLK * 4;
  int* np_part = (int*)(ws + off); off += NBLK * 4;
  int* np1_part = (int*)(ws + off); off += NBLK * 4;
  Acc* acc = (Acc*)(ws + off); off += sizeof(Acc);

  dim3 gbp(GX, BN);

  k_max<<<NBMAX, 256, 0, stream>>>(conf_data, bmax);
  k_best_truth<<<gbp, 256, 0, stream>>>(priors, targets, bto, bti);
  k_best_prior<<<(BN * ON) / 4, 256, 0, stream>>>(priors, targets, bpo, bpi);
  k_scatter<<<1, 64, 0, stream>>>(bmax, bpo, bpi, bto, bti, acc);
  k_encode<<<gbp, 256, 0, stream>>>(loc_data, conf_data, landm_data, priors, targets,
                                    bto, bti, lossc, posf, acc,
                                    part_l, part_lm, np_part, np1_part);
  k_select<<<BN, 256, 0, stream>>>(lossc, np_part, acc);
  k_conf_sum<<<gbp, 256, 0, stream>>>(conf_data, lossc, posf, acc, part_c);
  k_final<<<1, 256, 0, stream>>>(part_l, part_lm, part_c, np_part, np1_part, out);
}

// Round 3
// 315.260 us; speedup vs baseline: 6.1825x; 1.1818x over previous
//
#include <hip/hip_runtime.h>
#include <math.h>

#define BN 64
#define PN 16800
#define ON 64
#define THRESH 0.35f
#define NEGPOS 7
#define GX 66                 // blocks per row in p-dim (66*256 >= 16800)
#define NBLK (BN * GX)        // 4224 partial slots

// ---------- monotone float<->uint key (orderable as unsigned) ----------
__device__ __forceinline__ unsigned f2key(float f) {
  unsigned u = __float_as_uint(f);
  return (u & 0x80000000u) ? ~u : (u | 0x80000000u);
}
__device__ __forceinline__ float key2f(unsigned k) {
  unsigned u = (k & 0x80000000u) ? (k & 0x7FFFFFFFu) : ~k;
  return __uint_as_float(u);
}

struct Acc {
  unsigned xmax_key;   // global max of conf_data (encoded key)
};

__device__ __forceinline__ float sl1(float d) {
  float a = fabsf(d);
  return (a < 1.f) ? 0.5f * a * a : a - 0.5f;
}

// ---------- K1: per-prior best truth + per-block conf max ----------
__global__ void k_best_truth(const float* __restrict__ priors,
                             const float* __restrict__ targets,
                             const float* __restrict__ conf,
                             float* __restrict__ bto, int* __restrict__ bti,
                             unsigned* __restrict__ bmax) {
  int b = blockIdx.y;
  int tid = threadIdx.x;
  int p = blockIdx.x * 256 + tid;
  __shared__ float tb[ON][4];
  if (tid < ON * 4) {
    int t = tid >> 2, j = tid & 3;
    tb[t][j] = targets[(b * ON + t) * 15 + j];
  }
  __syncthreads();
  float cmax = -INFINITY;
  if (p < PN) {
    float2 c2 = reinterpret_cast<const float2*>(conf)[(long)b * PN + p];
    cmax = fmaxf(c2.x, c2.y);
    float4 pr = reinterpret_cast<const float4*>(priors)[p];
    float px1 = pr.x - pr.z * 0.5f, py1 = pr.y - pr.w * 0.5f;
    float px2 = pr.x + pr.z * 0.5f, py2 = pr.y + pr.w * 0.5f;
    float area_b = (px2 - px1) * (py2 - py1);
    float best = -1.f; int bidx = 0;
    for (int t = 0; t < ON; t++) {
      float ax1 = tb[t][0], ay1 = tb[t][1], ax2 = tb[t][2], ay2 = tb[t][3];
      float lx = fmaxf(ax1, px1), ly = fmaxf(ay1, py1);
      float rx = fminf(ax2, px2), ry = fminf(ay2, py2);
      float w = fmaxf(rx - lx, 0.f), h = fmaxf(ry - ly, 0.f);
      float inter = w * h;
      float area_a = (ax2 - ax1) * (ay2 - ay1);
      float iou = inter / (area_a + area_b - inter);
      if (iou > best) { best = iou; bidx = t; }
    }
    bto[b * PN + p] = best;
    bti[b * PN + p] = bidx;
  }
  // block-reduce conf max -> one partial per block
  for (int off = 32; off; off >>= 1) cmax = fmaxf(cmax, __shfl_down(cmax, off));
  __shared__ float wm[4];
  if ((tid & 63) == 0) wm[tid >> 6] = cmax;
  __syncthreads();
  if (tid == 0)
    bmax[b * GX + blockIdx.x] = f2key(fmaxf(fmaxf(wm[0], wm[1]), fmaxf(wm[2], wm[3])));
}

// ---------- K2: per-truth best prior (one BLOCK per (b,t)) ----------
__global__ void k_best_prior(const float* __restrict__ priors,
                             const float* __restrict__ targets,
                             float* __restrict__ bpo, int* __restrict__ bpi) {
  int pair = blockIdx.x;          // b*ON + t
  int tid = threadIdx.x;          // 256
  const float* tg = &targets[pair * 15];
  float ax1 = tg[0], ay1 = tg[1], ax2 = tg[2], ay2 = tg[3];
  float area_a = (ax2 - ax1) * (ay2 - ay1);
  float best = -1.f; int bidx = 0x7FFFFFFF;
  for (int p = tid; p < PN; p += 256) {
    float4 pr = reinterpret_cast<const float4*>(priors)[p];
    float px1 = pr.x - pr.z * 0.5f, py1 = pr.y - pr.w * 0.5f;
    float px2 = pr.x + pr.z * 0.5f, py2 = pr.y + pr.w * 0.5f;
    float lx = fmaxf(ax1, px1), ly = fmaxf(ay1, py1);
    float rx = fminf(ax2, px2), ry = fminf(ay2, py2);
    float w = fmaxf(rx - lx, 0.f), h = fmaxf(ry - ly, 0.f);
    float inter = w * h;
    float area_b = (px2 - px1) * (py2 - py1);
    float iou = inter / (area_a + area_b - inter);
    if (iou > best) { best = iou; bidx = p; }   // ascending p => first max kept
  }
  // wave reduce: larger wins; tie -> smaller index
  for (int off = 1; off < 64; off <<= 1) {
    float ov2 = __shfl_xor(best, off);
    int i2 = __shfl_xor(bidx, off);
    if (ov2 > best || (ov2 == best && i2 < bidx)) { best = ov2; bidx = i2; }
  }
  __shared__ float wbest[4]; __shared__ int widx[4];
  if ((tid & 63) == 0) { wbest[tid >> 6] = best; widx[tid >> 6] = bidx; }
  __syncthreads();
  if (tid == 0) {
    for (int w = 1; w < 4; w++)
      if (wbest[w] > best || (wbest[w] == best && widx[w] < bidx)) { best = wbest[w]; bidx = widx[w]; }
    bpo[pair] = best; bpi[pair] = bidx;
  }
}

// ---------- K3: reduce conf max + sequential scatter fixups ----------
__global__ void k_scatter(const unsigned* __restrict__ bmax,
                          const float* __restrict__ bpo, const int* __restrict__ bpi,
                          float* __restrict__ bto, int* __restrict__ bti, Acc* acc) {
  int tid = threadIdx.x;  // 256
  unsigned mk = 0;
  for (int i = tid; i < NBLK; i += 256) { unsigned v = bmax[i]; if (v > mk) mk = v; }
  for (int off = 1; off < 64; off <<= 1) {
    unsigned o = (unsigned)__shfl_xor((int)mk, off);
    if (o > mk) mk = o;
  }
  __shared__ unsigned wm[4];
  if ((tid & 63) == 0) wm[tid >> 6] = mk;
  __syncthreads();
  if (tid == 0) {
    unsigned m = wm[0];
    if (wm[1] > m) m = wm[1];
    if (wm[2] > m) m = wm[2];
    if (wm[3] > m) m = wm[3];
    acc->xmax_key = m;
  }
  if (tid < BN) {
    int b = tid;
    int idxs[ON];
    float orig[ON];
    for (int t = 0; t < ON; t++) idxs[t] = bpi[b * ON + t];
    for (int t = 0; t < ON; t++) orig[t] = bto[b * PN + idxs[t]];  // pre-update gather
    for (int t = 0; t < ON; t++) {
      bool valid = bpo[b * ON + t] >= 0.2f;
      bto[b * PN + idxs[t]] = valid ? 2.0f : orig[t];
      bti[b * PN + idxs[t]] = t;  // unconditional in reference
    }
  }
}

// ---------- K4: encode + smooth-l1 + loss_c + per-block partials ----------
__global__ void k_encode(const float* __restrict__ loc_data,
                         const float* __restrict__ conf_data,
                         const float* __restrict__ landm_data,
                         const float* __restrict__ priors,
                         const float* __restrict__ targets,
                         const float* __restrict__ bto, const int* __restrict__ bti,
                         float* __restrict__ lossc, unsigned char* __restrict__ posf,
                         const Acc* __restrict__ acc,
                         float* __restrict__ part_l, float* __restrict__ part_lm,
                         int* __restrict__ np_part, int* __restrict__ np1_part) {
  int b = blockIdx.y;
  int p = blockIdx.x * 256 + threadIdx.x;
  int bid = b * GX + blockIdx.x;
  float sum_l = 0.f, sum_lm = 0.f;
  int cp = 0, cp1 = 0;
  if (p < PN) {
    int t = bti[b * PN + p];
    float ov = bto[b * PN + p];
    const float* tg = &targets[(b * ON + t) * 15];
    float label = tg[14];
    float conf = (ov < THRESH) ? 0.f : label;
    bool pos = (conf != 0.f);
    bool pos1 = (conf > 0.f);
    float4 pr = reinterpret_cast<const float4*>(priors)[p];
    if (pos) {
      float m0 = tg[0], m1 = tg[1], m2 = tg[2], m3 = tg[3];
      float g0 = ((m0 + m2) * 0.5f - pr.x) / (0.1f * pr.z);
      float g1 = ((m1 + m3) * 0.5f - pr.y) / (0.1f * pr.w);
      float g2 = logf((m2 - m0) / pr.z) / 0.2f;
      float g3 = logf((m3 - m1) / pr.w) / 0.2f;
      const float* ld = &loc_data[((long)b * PN + p) * 4];
      sum_l = sl1(ld[0] - g0) + sl1(ld[1] - g1) + sl1(ld[2] - g2) + sl1(ld[3] - g3);
      cp = 1;
    }
    if (pos1) {
      const float* lm = &landm_data[((long)b * PN + p) * 10];
      for (int i = 0; i < 5; i++) {
        float gx = (tg[4 + 2 * i] - pr.x) / (0.1f * pr.z);
        float gy = (tg[5 + 2 * i] - pr.y) / (0.1f * pr.w);
        sum_lm += sl1(lm[2 * i] - gx) + sl1(lm[2 * i + 1] - gy);
      }
      cp1 = 1;
    }
    float2 c2 = reinterpret_cast<const float2*>(conf_data)[(long)b * PN + p];
    float xmax = key2f(acc->xmax_key);
    float lse = logf(expf(c2.x - xmax) + expf(c2.y - xmax)) + xmax;
    lossc[b * PN + p] = lse - (pos ? c2.y : c2.x);
    posf[b * PN + p] = pos ? 1 : 0;
  }
  // block reduce -> one partial store per block (no global atomics)
  for (int off = 32; off; off >>= 1) {
    sum_l += __shfl_down(sum_l, off);
    sum_lm += __shfl_down(sum_lm, off);
    cp += __shfl_down(cp, off);
    cp1 += __shfl_down(cp1, off);
  }
  __shared__ float sl4[4], slm4[4];
  __shared__ int sp4[4], sp14[4];
  int w = threadIdx.x >> 6;
  if ((threadIdx.x & 63) == 0) { sl4[w] = sum_l; slm4[w] = sum_lm; sp4[w] = cp; sp14[w] = cp1; }
  __syncthreads();
  if (threadIdx.x == 0) {
    part_l[bid] = sl4[0] + sl4[1] + sl4[2] + sl4[3];
    part_lm[bid] = slm4[0] + slm4[1] + slm4[2] + slm4[3];
    np_part[bid] = sp4[0] + sp4[1] + sp4[2] + sp4[3];
    np1_part[bid] = sp14[0] + sp14[1] + sp14[2] + sp14[3];
  }
}

// ---------- K5: per-row radix select + fused CE sum ----------
__global__ void __launch_bounds__(1024) k_select_sum(const float* __restrict__ lossc,
                                                     const unsigned char* __restrict__ posf,
                                                     const int* __restrict__ np_part,
                                                     float* __restrict__ part_c) {
  int b = blockIdx.x;
  int tid = threadIdx.x;
  __shared__ unsigned hist[256], suf[256];
  __shared__ unsigned s_chosen, s_rem;
  __shared__ int s_np;
  const float* row = &lossc[(long)b * PN];
  const unsigned char* prow = &posf[(long)b * PN];

  if (tid == 0) s_np = 0;
  __syncthreads();
  if (tid < GX) atomicAdd(&s_np, np_part[b * GX + tid]);
  __syncthreads();
  int np = s_np;
  long k = (long)NEGPOS * np;
  if (k > PN - 1) k = PN - 1;

  unsigned T = 0xFFFFFFFFu, R = 0, C = 0;
  if (k > 0) {
    unsigned prefix = 0, remaining = (unsigned)k, lastC = 0;
    for (int pass = 0; pass < 4; pass++) {
      int shift = 24 - pass * 8;
      if (tid < 256) hist[tid] = 0;
      __syncthreads();
      unsigned hmask = (pass == 0) ? 0u : (0xFFFFFFFFu << (shift + 8));
      for (int p = tid; p < PN; p += 1024) {
        unsigned key = f2key(row[p]);
        if (((key ^ prefix) & hmask) == 0)
          atomicAdd(&hist[(key >> shift) & 255], 1u);
      }
      __syncthreads();
      if (tid < 256) suf[tid] = hist[tid];
      __syncthreads();
      for (int off = 1; off < 256; off <<= 1) {
        unsigned tv = 0;
        if (tid < 256 && tid + off < 256) tv = suf[tid + off];
        __syncthreads();
        if (tid < 256) suf[tid] += tv;
        __syncthreads();
      }
      if (tid < 256) {
        unsigned nextS = (tid < 255) ? suf[tid + 1] : 0;
        if (suf[tid] >= remaining && nextS < remaining) {  // unique crossing
          s_chosen = (unsigned)tid;
          s_rem = remaining - nextS;
        }
      }
      __syncthreads();
      prefix |= s_chosen << shift;
      remaining = s_rem;
      if (pass == 3) lastC = hist[s_chosen];
      __syncthreads();
    }
    T = prefix; R = remaining; C = lastC;
  }

  // fused CE sum: selected = pos | neg; CE value IS lossc (lse - gathered)
  float s = 0.f;
  bool fastTies = (R > 0 && C == R);
  for (int p = tid; p < PN; p += 1024) {
    bool pos = prow[p] != 0;
    float v = row[p];
    unsigned key = f2key(v);
    bool sel = pos || (R > 0 && (key > T || (key == T && fastTies)));
    if (sel) s += v;
  }
  // rare path: more ties than slots -> wave 0 ranks ties in index order
  if (R > 0 && C != R && tid < 64) {
    unsigned running = 0;
    for (int base = 0; base < PN; base += 64) {
      int p = base + tid;
      bool tie = false, pos = false;
      float v = 0.f;
      if (p < PN) {
        v = row[p];
        tie = (f2key(v) == T);
        pos = prow[p] != 0;
      }
      unsigned long long m = __ballot(tie);
      if (tie) {
        unsigned rank = running + (unsigned)__popcll(m & ((1ull << tid) - 1));
        if (rank < R && !pos) s += v;   // pos already counted in main pass
      }
      running += (unsigned)__popcll(m);
    }
  }
  // block reduce 1024 threads
  for (int off = 32; off; off >>= 1) s += __shfl_down(s, off);
  __shared__ float ws[16];
  if ((tid & 63) == 0) ws[tid >> 6] = s;
  __syncthreads();
  if (tid == 0) {
    float tot = 0.f;
    for (int i = 0; i < 16; i++) tot += ws[i];
    part_c[b] = tot;
  }
}

// ---------- K6: reduce all partials, finalize three scalars ----------
__global__ void k_final(const float* __restrict__ part_l, const float* __restrict__ part_lm,
                        const float* __restrict__ part_c,
                        const int* __restrict__ np_part, const int* __restrict__ np1_part,
                        float* __restrict__ out) {
  float sl = 0.f, slm = 0.f, sc = 0.f;
  int np = 0, np1 = 0;
  for (int i = threadIdx.x; i < NBLK; i += 256) {
    sl += part_l[i]; slm += part_lm[i];
    np += np_part[i]; np1 += np1_part[i];
  }
  if (threadIdx.x < BN) sc = part_c[threadIdx.x];
  for (int off = 32; off; off >>= 1) {
    sl += __shfl_down(sl, off); slm += __shfl_down(slm, off); sc += __shfl_down(sc, off);
    np += __shfl_down(np, off); np1 += __shfl_down(np1, off);
  }
  __shared__ float a[4], bsh[4], c[4];
  __shared__ int d[4], e[4];
  int w = threadIdx.x >> 6;
  if ((threadIdx.x & 63) == 0) { a[w] = sl; bsh[w] = slm; c[w] = sc; d[w] = np; e[w] = np1; }
  __syncthreads();
  if (threadIdx.x == 0) {
    float N = fmaxf((float)(d[0] + d[1] + d[2] + d[3]), 1.f);
    float N1 = fmaxf((float)(e[0] + e[1] + e[2] + e[3]), 1.f);
    out[0] = (a[0] + a[1] + a[2] + a[3]) / N;
    out[1] = (c[0] + c[1] + c[2] + c[3]) / N;
    out[2] = (bsh[0] + bsh[1] + bsh[2] + bsh[3]) / N1;
  }
}

extern "C" void kernel_launch(void* const* d_in, const int* in_sizes, int n_in,
                              void* d_out, int out_size, void* d_ws, size_t ws_size,
                              hipStream_t stream) {
  const float* loc_data = (const float*)d_in[0];
  const float* conf_data = (const float*)d_in[1];
  const float* landm_data = (const float*)d_in[2];
  const float* priors = (const float*)d_in[3];
  const float* targets = (const float*)d_in[4];
  float* out = (float*)d_out;

  char* ws = (char*)d_ws;
  const size_t SZ = (size_t)BN * PN * 4;  // 4.3 MB per float array
  size_t off = 0;
  float* lossc = (float*)(ws + off); off += SZ;
  float* bto = (float*)(ws + off); off += SZ;
  int* bti = (int*)(ws + off); off += SZ;
  unsigned char* posf = (unsigned char*)(ws + off); off += (size_t)BN * PN;
  off = (off + 15) & ~(size_t)15;
  float* bpo = (float*)(ws + off); off += (size_t)BN * ON * 4;
  int* bpi = (int*)(ws + off); off += (size_t)BN * ON * 4;
  unsigned* bmax = (unsigned*)(ws + off); off += NBLK * 4;
  float* part_l = (float*)(ws + off); off += NBLK * 4;
  float* part_lm = (float*)(ws + off); off += NBLK * 4;
  float* part_c = (float*)(ws + off); off += BN * 4;
  int* np_part = (int*)(ws + off); off += NBLK * 4;
  int* np1_part = (int*)(ws + off); off += NBLK * 4;
  Acc* acc = (Acc*)(ws + off); off += sizeof(Acc);

  dim3 gbp(GX, BN);

  k_best_truth<<<gbp, 256, 0, stream>>>(priors, targets, conf_data, bto, bti, bmax);
  k_best_prior<<<BN * ON, 256, 0, stream>>>(priors, targets, bpo, bpi);
  k_scatter<<<1, 256, 0, stream>>>(bmax, bpo, bpi, bto, bti, acc);
  k_encode<<<gbp, 256, 0, stream>>>(loc_data, conf_data, landm_data, priors, targets,
                                    bto, bti, lossc, posf, acc,
                                    part_l, part_lm, np_part, np1_part);
  k_select_sum<<<BN, 1024, 0, stream>>>(lossc, posf, np_part, part_c);
  k_final<<<1, 256, 0, stream>>>(part_l, part_lm, part_c, np_part, np1_part, out);
}

// Round 4
// 231.234 us; speedup vs baseline: 8.4291x; 1.3634x over previous
//
#include <hip/hip_runtime.h>
#include <math.h>

#define BN 64
#define PN 16800
#define ON 64
#define THRESH 0.35f
#define NEGPOS 7
#define GX 66                 // blocks per row in p-dim (66*256 >= 16800)
#define NBLK (BN * GX)        // 4224 partial slots
#define TG 4                  // truths per block in k_best_prior

// ---------- monotone float<->uint key (orderable as unsigned) ----------
__device__ __forceinline__ unsigned f2key(float f) {
  unsigned u = __float_as_uint(f);
  return (u & 0x80000000u) ? ~u : (u | 0x80000000u);
}
__device__ __forceinline__ float key2f(unsigned k) {
  unsigned u = (k & 0x80000000u) ? (k & 0x7FFFFFFFu) : ~k;
  return __uint_as_float(u);
}

struct Acc {
  unsigned xmax_key;   // global max of conf_data (encoded key)
};

__device__ __forceinline__ float sl1(float d) {
  float a = fabsf(d);
  return (a < 1.f) ? 0.5f * a * a : a - 0.5f;
}

// ---------- K1: per-prior best truth (cross-mult argmax) + per-block conf max ----------
__global__ void k_best_truth(const float* __restrict__ priors,
                             const float* __restrict__ targets,
                             const float* __restrict__ conf,
                             float* __restrict__ bto, int* __restrict__ bti,
                             unsigned* __restrict__ bmax) {
  int b = blockIdx.y;
  int tid = threadIdx.x;
  int p = blockIdx.x * 256 + tid;
  float cmax = -INFINITY;
  if (p < PN) {
    float2 c2 = reinterpret_cast<const float2*>(conf)[(long)b * PN + p];
    cmax = fmaxf(c2.x, c2.y);
    float4 pr = reinterpret_cast<const float4*>(priors)[p];
    float px1 = pr.x - pr.z * 0.5f, py1 = pr.y - pr.w * 0.5f;
    float px2 = pr.x + pr.z * 0.5f, py2 = pr.y + pr.w * 0.5f;
    float area_b = (px2 - px1) * (py2 - py1);
    float bi = -1.f, bu = 1.f;  // best inter/union as fraction (no division in loop)
    int bidx = 0;
    const float* tgb = &targets[(long)b * ON * 15];
    for (int t = 0; t < ON; t++) {
      float ax1 = tgb[t * 15 + 0], ay1 = tgb[t * 15 + 1];
      float ax2 = tgb[t * 15 + 2], ay2 = tgb[t * 15 + 3];   // wave-uniform -> s_load
      float lx = fmaxf(ax1, px1), ly = fmaxf(ay1, py1);
      float rx = fminf(ax2, px2), ry = fminf(ay2, py2);
      float w = fmaxf(rx - lx, 0.f), h = fmaxf(ry - ly, 0.f);
      float inter = w * h;
      float area_a = (ax2 - ax1) * (ay2 - ay1);
      float uni = area_a + area_b - inter;
      // inter/uni > bi/bu  <=>  inter*bu > bi*uni  (uni,bu > 0)
      if (inter * bu > bi * uni) { bi = inter; bu = uni; bidx = t; }
    }
    bto[b * PN + p] = bi / bu;   // single division, same operands as reference
    bti[b * PN + p] = bidx;
  }
  for (int off = 32; off; off >>= 1) cmax = fmaxf(cmax, __shfl_down(cmax, off));
  __shared__ float wm[4];
  if ((tid & 63) == 0) wm[tid >> 6] = cmax;
  __syncthreads();
  if (tid == 0)
    bmax[b * GX + blockIdx.x] = f2key(fmaxf(fmaxf(wm[0], wm[1]), fmaxf(wm[2], wm[3])));
}

// ---------- K2: per-truth best prior (one block per (b, 4 truths)) ----------
__global__ void k_best_prior(const float* __restrict__ priors,
                             const float* __restrict__ targets,
                             float* __restrict__ bpo, int* __restrict__ bpi) {
  int bx = blockIdx.x;            // 1024 blocks: b = bx>>4, truth group g = bx&15
  int b = bx >> 4;
  int t0 = (bx & 15) * TG;
  int tid = threadIdx.x;
  float ax1[TG], ay1[TG], ax2[TG], ay2[TG], area_a[TG];
#pragma unroll
  for (int i = 0; i < TG; i++) {
    const float* tg = &targets[((long)b * ON + t0 + i) * 15];
    ax1[i] = tg[0]; ay1[i] = tg[1]; ax2[i] = tg[2]; ay2[i] = tg[3];
    area_a[i] = (ax2[i] - ax1[i]) * (ay2[i] - ay1[i]);
  }
  float bi[TG], bu[TG]; int bp[TG];
#pragma unroll
  for (int i = 0; i < TG; i++) { bi[i] = -1.f; bu[i] = 1.f; bp[i] = 0x7FFFFFFF; }
  for (int p = tid; p < PN; p += 256) {
    float4 pr = reinterpret_cast<const float4*>(priors)[p];
    float px1 = pr.x - pr.z * 0.5f, py1 = pr.y - pr.w * 0.5f;
    float px2 = pr.x + pr.z * 0.5f, py2 = pr.y + pr.w * 0.5f;
    float area_b = (px2 - px1) * (py2 - py1);
#pragma unroll
    for (int i = 0; i < TG; i++) {
      float lx = fmaxf(ax1[i], px1), ly = fmaxf(ay1[i], py1);
      float rx = fminf(ax2[i], px2), ry = fminf(ay2[i], py2);
      float w = fmaxf(rx - lx, 0.f), h = fmaxf(ry - ly, 0.f);
      float inter = w * h;
      float uni = area_a[i] + area_b - inter;
      if (inter * bu[i] > bi[i] * uni) { bi[i] = inter; bu[i] = uni; bp[i] = p; }
    }
  }
  // wave butterfly: larger fraction wins; exact product tie -> smaller index
#pragma unroll
  for (int off = 1; off < 64; off <<= 1) {
#pragma unroll
    for (int i = 0; i < TG; i++) {
      float oi = __shfl_xor(bi[i], off), ou = __shfl_xor(bu[i], off);
      int op = __shfl_xor(bp[i], off);
      float a = oi * bu[i], c = bi[i] * ou;
      if (a > c || (a == c && op < bp[i])) { bi[i] = oi; bu[i] = ou; bp[i] = op; }
    }
  }
  __shared__ float si[TG][4], su[TG][4];
  __shared__ int sp[TG][4];
  int w = tid >> 6;
  if ((tid & 63) == 0) {
#pragma unroll
    for (int i = 0; i < TG; i++) { si[i][w] = bi[i]; su[i][w] = bu[i]; sp[i][w] = bp[i]; }
  }
  __syncthreads();
  if (tid < TG) {
    float fi = si[tid][0], fu = su[tid][0]; int fp = sp[tid][0];
    for (int ww = 1; ww < 4; ww++) {
      float a = si[tid][ww] * fu, c = fi * su[tid][ww];
      if (a > c || (a == c && sp[tid][ww] < fp)) { fi = si[tid][ww]; fu = su[tid][ww]; fp = sp[tid][ww]; }
    }
    bpo[(long)b * ON + t0 + tid] = fi / fu;
    bpi[(long)b * ON + t0 + tid] = fp;
  }
}

// ---------- K3: parallel scatter (winner = last t per target) + conf-max reduce ----------
__global__ void k_scatter(const unsigned* __restrict__ bmax,
                          const float* __restrict__ bpo, const int* __restrict__ bpi,
                          float* __restrict__ bto, int* __restrict__ bti, Acc* acc) {
  int tid = threadIdx.x;
  if (blockIdx.x == 16) {  // conf-max reduction block
    unsigned mk = 0;
    for (int i = tid; i < NBLK; i += 256) { unsigned v = bmax[i]; if (v > mk) mk = v; }
    for (int off = 1; off < 64; off <<= 1) {
      unsigned o = (unsigned)__shfl_xor((int)mk, off);
      if (o > mk) mk = o;
    }
    __shared__ unsigned wm[4];
    if ((tid & 63) == 0) wm[tid >> 6] = mk;
    __syncthreads();
    if (tid == 0) {
      unsigned m = wm[0];
      if (wm[1] > m) m = wm[1];
      if (wm[2] > m) m = wm[2];
      if (wm[3] > m) m = wm[3];
      acc->xmax_key = m;
    }
    return;
  }
  // blocks 0..15: 4 rows per block, one wave per row, lane = t
  int row = blockIdx.x * 4 + (tid >> 6);   // batch row b
  int t = tid & 63;
  int q = bpi[row * ON + t];
  bool valid = bpo[row * ON + t] >= 0.2f;
  // winner iff no t' > t maps to same q (last-write-wins)
  bool dupLater = false;
  for (int j = 0; j < 64; j++) {
    int ij = __shfl(q, j);
    if (j > t && ij == q) dupLater = true;
  }
  if (!dupLater) {
    bti[(long)row * PN + q] = t;           // unconditional arange write
    if (valid) bto[(long)row * PN + q] = 2.0f;  // else writes back original: no-op
  }
}

// ---------- K4: encode + smooth-l1 + loss_c + per-block partials ----------
__global__ void k_encode(const float* __restrict__ loc_data,
                         const float* __restrict__ conf_data,
                         const float* __restrict__ landm_data,
                         const float* __restrict__ priors,
                         const float* __restrict__ targets,
                         const float* __restrict__ bto, const int* __restrict__ bti,
                         float* __restrict__ lossc, unsigned char* __restrict__ posf,
                         const Acc* __restrict__ acc,
                         float* __restrict__ part_l, float* __restrict__ part_lm,
                         int* __restrict__ np_part, int* __restrict__ np1_part) {
  int b = blockIdx.y;
  int p = blockIdx.x * 256 + threadIdx.x;
  int bid = b * GX + blockIdx.x;
  float sum_l = 0.f, sum_lm = 0.f;
  int cp = 0, cp1 = 0;
  if (p < PN) {
    int t = bti[b * PN + p];
    float ov = bto[b * PN + p];
    const float* tg = &targets[(b * ON + t) * 15];
    float label = tg[14];
    float conf = (ov < THRESH) ? 0.f : label;
    bool pos = (conf != 0.f);
    bool pos1 = (conf > 0.f);
    float4 pr = reinterpret_cast<const float4*>(priors)[p];
    if (pos) {
      float m0 = tg[0], m1 = tg[1], m2 = tg[2], m3 = tg[3];
      float g0 = ((m0 + m2) * 0.5f - pr.x) / (0.1f * pr.z);
      float g1 = ((m1 + m3) * 0.5f - pr.y) / (0.1f * pr.w);
      float g2 = logf((m2 - m0) / pr.z) / 0.2f;
      float g3 = logf((m3 - m1) / pr.w) / 0.2f;
      const float* ld = &loc_data[((long)b * PN + p) * 4];
      sum_l = sl1(ld[0] - g0) + sl1(ld[1] - g1) + sl1(ld[2] - g2) + sl1(ld[3] - g3);
      cp = 1;
    }
    if (pos1) {
      const float* lm = &landm_data[((long)b * PN + p) * 10];
      for (int i = 0; i < 5; i++) {
        float gx = (tg[4 + 2 * i] - pr.x) / (0.1f * pr.z);
        float gy = (tg[5 + 2 * i] - pr.y) / (0.1f * pr.w);
        sum_lm += sl1(lm[2 * i] - gx) + sl1(lm[2 * i + 1] - gy);
      }
      cp1 = 1;
    }
    float2 c2 = reinterpret_cast<const float2*>(conf_data)[(long)b * PN + p];
    float xmax = key2f(acc->xmax_key);
    float lse = logf(expf(c2.x - xmax) + expf(c2.y - xmax)) + xmax;
    lossc[b * PN + p] = lse - (pos ? c2.y : c2.x);
    posf[b * PN + p] = pos ? 1 : 0;
  }
  for (int off = 32; off; off >>= 1) {
    sum_l += __shfl_down(sum_l, off);
    sum_lm += __shfl_down(sum_lm, off);
    cp += __shfl_down(cp, off);
    cp1 += __shfl_down(cp1, off);
  }
  __shared__ float sl4[4], slm4[4];
  __shared__ int sp4[4], sp14[4];
  int w = threadIdx.x >> 6;
  if ((threadIdx.x & 63) == 0) { sl4[w] = sum_l; slm4[w] = sum_lm; sp4[w] = cp; sp14[w] = cp1; }
  __syncthreads();
  if (threadIdx.x == 0) {
    part_l[bid] = sl4[0] + sl4[1] + sl4[2] + sl4[3];
    part_lm[bid] = slm4[0] + slm4[1] + slm4[2] + slm4[3];
    np_part[bid] = sp4[0] + sp4[1] + sp4[2] + sp4[3];
    np1_part[bid] = sp14[0] + sp14[1] + sp14[2] + sp14[3];
  }
}

// ---------- K5: per-row radix select + fused CE sum ----------
__global__ void __launch_bounds__(1024) k_select_sum(const float* __restrict__ lossc,
                                                     const unsigned char* __restrict__ posf,
                                                     const int* __restrict__ np_part,
                                                     float* __restrict__ part_c) {
  int b = blockIdx.x;
  int tid = threadIdx.x;
  __shared__ unsigned hist[256], suf[256];
  __shared__ unsigned s_chosen, s_rem;
  __shared__ int s_np;
  const float* row = &lossc[(long)b * PN];
  const unsigned char* prow = &posf[(long)b * PN];

  if (tid == 0) s_np = 0;
  __syncthreads();
  if (tid < GX) atomicAdd(&s_np, np_part[b * GX + tid]);
  __syncthreads();
  int np = s_np;
  long k = (long)NEGPOS * np;
  if (k > PN - 1) k = PN - 1;

  unsigned T = 0xFFFFFFFFu, R = 0, C = 0;
  if (k > 0) {
    unsigned prefix = 0, remaining = (unsigned)k, lastC = 0;
    for (int pass = 0; pass < 4; pass++) {
      int shift = 24 - pass * 8;
      if (tid < 256) hist[tid] = 0;
      __syncthreads();
      unsigned hmask = (pass == 0) ? 0u : (0xFFFFFFFFu << (shift + 8));
      for (int p = tid; p < PN; p += 1024) {
        unsigned key = f2key(row[p]);
        if (((key ^ prefix) & hmask) == 0)
          atomicAdd(&hist[(key >> shift) & 255], 1u);
      }
      __syncthreads();
      if (tid < 256) suf[tid] = hist[tid];
      __syncthreads();
      for (int off = 1; off < 256; off <<= 1) {
        unsigned tv = 0;
        if (tid < 256 && tid + off < 256) tv = suf[tid + off];
        __syncthreads();
        if (tid < 256) suf[tid] += tv;
        __syncthreads();
      }
      if (tid < 256) {
        unsigned nextS = (tid < 255) ? suf[tid + 1] : 0;
        if (suf[tid] >= remaining && nextS < remaining) {
          s_chosen = (unsigned)tid;
          s_rem = remaining - nextS;
        }
      }
      __syncthreads();
      prefix |= s_chosen << shift;
      remaining = s_rem;
      if (pass == 3) lastC = hist[s_chosen];
      __syncthreads();
    }
    T = prefix; R = remaining; C = lastC;
  }

  float s = 0.f;
  bool fastTies = (R > 0 && C == R);
  for (int p = tid; p < PN; p += 1024) {
    bool pos = prow[p] != 0;
    float v = row[p];
    unsigned key = f2key(v);
    bool sel = pos || (R > 0 && (key > T || (key == T && fastTies)));
    if (sel) s += v;
  }
  if (R > 0 && C != R && tid < 64) {  // rare tie path
    unsigned running = 0;
    for (int base = 0; base < PN; base += 64) {
      int p = base + tid;
      bool tie = false, pos = false;
      float v = 0.f;
      if (p < PN) {
        v = row[p];
        tie = (f2key(v) == T);
        pos = prow[p] != 0;
      }
      unsigned long long m = __ballot(tie);
      if (tie) {
        unsigned rank = running + (unsigned)__popcll(m & ((1ull << tid) - 1));
        if (rank < R && !pos) s += v;
      }
      running += (unsigned)__popcll(m);
    }
  }
  for (int off = 32; off; off >>= 1) s += __shfl_down(s, off);
  __shared__ float ws[16];
  if ((tid & 63) == 0) ws[tid >> 6] = s;
  __syncthreads();
  if (tid == 0) {
    float tot = 0.f;
    for (int i = 0; i < 16; i++) tot += ws[i];
    part_c[b] = tot;
  }
}

// ---------- K6: reduce all partials, finalize three scalars ----------
__global__ void k_final(const float* __restrict__ part_l, const float* __restrict__ part_lm,
                        const float* __restrict__ part_c,
                        const int* __restrict__ np_part, const int* __restrict__ np1_part,
                        float* __restrict__ out) {
  float sl = 0.f, slm = 0.f, sc = 0.f;
  int np = 0, np1 = 0;
  for (int i = threadIdx.x; i < NBLK; i += 256) {
    sl += part_l[i]; slm += part_lm[i];
    np += np_part[i]; np1 += np1_part[i];
  }
  if (threadIdx.x < BN) sc = part_c[threadIdx.x];
  for (int off = 32; off; off >>= 1) {
    sl += __shfl_down(sl, off); slm += __shfl_down(slm, off); sc += __shfl_down(sc, off);
    np += __shfl_down(np, off); np1 += __shfl_down(np1, off);
  }
  __shared__ float a[4], bsh[4], c[4];
  __shared__ int d[4], e[4];
  int w = threadIdx.x >> 6;
  if ((threadIdx.x & 63) == 0) { a[w] = sl; bsh[w] = slm; c[w] = sc; d[w] = np; e[w] = np1; }
  __syncthreads();
  if (threadIdx.x == 0) {
    float N = fmaxf((float)(d[0] + d[1] + d[2] + d[3]), 1.f);
    float N1 = fmaxf((float)(e[0] + e[1] + e[2] + e[3]), 1.f);
    out[0] = (a[0] + a[1] + a[2] + a[3]) / N;
    out[1] = (c[0] + c[1] + c[2] + c[3]) / N;
    out[2] = (bsh[0] + bsh[1] + bsh[2] + bsh[3]) / N1;
  }
}

extern "C" void kernel_launch(void* const* d_in, const int* in_sizes, int n_in,
                              void* d_out, int out_size, void* d_ws, size_t ws_size,
                              hipStream_t stream) {
  const float* loc_data = (const float*)d_in[0];
  const float* conf_data = (const float*)d_in[1];
  const float* landm_data = (const float*)d_in[2];
  const float* priors = (const float*)d_in[3];
  const float* targets = (const float*)d_in[4];
  float* out = (float*)d_out;

  char* ws = (char*)d_ws;
  const size_t SZ = (size_t)BN * PN * 4;
  size_t off = 0;
  float* lossc = (float*)(ws + off); off += SZ;
  float* bto = (float*)(ws + off); off += SZ;
  int* bti = (int*)(ws + off); off += SZ;
  unsigned char* posf = (unsigned char*)(ws + off); off += (size_t)BN * PN;
  off = (off + 15) & ~(size_t)15;
  float* bpo = (float*)(ws + off); off += (size_t)BN * ON * 4;
  int* bpi = (int*)(ws + off); off += (size_t)BN * ON * 4;
  unsigned* bmax = (unsigned*)(ws + off); off += NBLK * 4;
  float* part_l = (float*)(ws + off); off += NBLK * 4;
  float* part_lm = (float*)(ws + off); off += NBLK * 4;
  float* part_c = (float*)(ws + off); off += BN * 4;
  int* np_part = (int*)(ws + off); off += NBLK * 4;
  int* np1_part = (int*)(ws + off); off += NBLK * 4;
  Acc* acc = (Acc*)(ws + off); off += sizeof(Acc);

  dim3 gbp(GX, BN);

  k_best_truth<<<gbp, 256, 0, stream>>>(priors, targets, conf_data, bto, bti, bmax);
  k_best_prior<<<BN * (ON / TG), 256, 0, stream>>>(priors, targets, bpo, bpi);
  k_scatter<<<17, 256, 0, stream>>>(bmax, bpo, bpi, bto, bti, acc);
  k_encode<<<gbp, 256, 0, stream>>>(loc_data, conf_data, landm_data, priors, targets,
                                    bto, bti, lossc, posf, acc,
                                    part_l, part_lm, np_part, np1_part);
  k_select_sum<<<BN, 1024, 0, stream>>>(lossc, posf, np_part, part_c);
  k_final<<<1, 256, 0, stream>>>(part_l, part_lm, part_c, np_part, np1_part, out);
}

// Round 5
// 230.915 us; speedup vs baseline: 8.4408x; 1.0014x over previous
//
#include <hip/hip_runtime.h>
#include <math.h>

#define BN 64
#define PN 16800
#define ON 64
#define THRESH 0.35f
#define NEGPOS 7
#define GX 66                 // blocks per row in p-dim for encode (66*256 >= 16800)
#define NBLK (BN * GX)        // 4224 partial slots
#define GXB 33                // blocks per row for best_truth (33*512 >= 16800)
#define NB_BT (BN * GXB)      // 2112 bmax slots
#define TG 4                  // truths per block in k_best_prior

// ---------- monotone float<->uint key (orderable as unsigned) ----------
__device__ __forceinline__ unsigned f2key(float f) {
  unsigned u = __float_as_uint(f);
  return (u & 0x80000000u) ? ~u : (u | 0x80000000u);
}
__device__ __forceinline__ float key2f(unsigned k) {
  unsigned u = (k & 0x80000000u) ? (k & 0x7FFFFFFFu) : ~k;
  return __uint_as_float(u);
}

struct Acc {
  unsigned xmax_key;   // global max of conf_data (encoded key)
};

__device__ __forceinline__ float sl1(float d) {
  float a = fabsf(d);
  return (a < 1.f) ? 0.5f * a * a : a - 0.5f;
}

// ---------- K1: per-prior best truth, 2 priors/thread, LDS-staged truths ----------
__global__ void k_best_truth(const float* __restrict__ priors,
                             const float* __restrict__ targets,
                             const float* __restrict__ conf,
                             float* __restrict__ bto, int* __restrict__ bti,
                             unsigned* __restrict__ bmax) {
  int b = blockIdx.y;
  int tid = threadIdx.x;
  int p0 = blockIdx.x * 512 + tid;        // always < PN (33rd block: <=16639)
  int p1 = p0 + 256;                      // may exceed PN in last block
  bool v1 = p1 < PN;

  __shared__ float4 tbox[ON];
  __shared__ float tarea[ON];
  if (tid < ON) {
    const float* tg = &targets[((long)b * ON + tid) * 15];
    float4 bx = make_float4(tg[0], tg[1], tg[2], tg[3]);
    tbox[tid] = bx;
    tarea[tid] = (bx.z - bx.x) * (bx.w - bx.y);
  }
  __syncthreads();

  float2 c0 = reinterpret_cast<const float2*>(conf)[(long)b * PN + p0];
  float cmax = fmaxf(c0.x, c0.y);
  if (v1) {
    float2 c1 = reinterpret_cast<const float2*>(conf)[(long)b * PN + p1];
    cmax = fmaxf(cmax, fmaxf(c1.x, c1.y));
  }

  float4 prA = reinterpret_cast<const float4*>(priors)[p0];
  float4 prB = reinterpret_cast<const float4*>(priors)[v1 ? p1 : p0];
  float ax1A = prA.x - prA.z * 0.5f, ay1A = prA.y - prA.w * 0.5f;
  float ax2A = prA.x + prA.z * 0.5f, ay2A = prA.y + prA.w * 0.5f;
  float abA = (ax2A - ax1A) * (ay2A - ay1A);
  float ax1B = prB.x - prB.z * 0.5f, ay1B = prB.y - prB.w * 0.5f;
  float ax2B = prB.x + prB.z * 0.5f, ay2B = prB.y + prB.w * 0.5f;
  float abB = (ax2B - ax1B) * (ay2B - ay1B);

  float biA = -1.f, buA = 1.f, biB = -1.f, buB = 1.f;
  int idA = 0, idB = 0;
#pragma unroll 4
  for (int t = 0; t < ON; t++) {
    float4 a = tbox[t];
    float aa = tarea[t];
    // prior A
    {
      float lx = fmaxf(a.x, ax1A), ly = fmaxf(a.y, ay1A);
      float rx = fminf(a.z, ax2A), ry = fminf(a.w, ay2A);
      float w = fmaxf(rx - lx, 0.f), h = fmaxf(ry - ly, 0.f);
      float inter = w * h;
      float uni = aa + abA - inter;
      if (inter * buA > biA * uni) { biA = inter; buA = uni; idA = t; }
    }
    // prior B
    {
      float lx = fmaxf(a.x, ax1B), ly = fmaxf(a.y, ay1B);
      float rx = fminf(a.z, ax2B), ry = fminf(a.w, ay2B);
      float w = fmaxf(rx - lx, 0.f), h = fmaxf(ry - ly, 0.f);
      float inter = w * h;
      float uni = aa + abB - inter;
      if (inter * buB > biB * uni) { biB = inter; buB = uni; idB = t; }
    }
  }
  bto[b * PN + p0] = biA / buA;
  bti[b * PN + p0] = idA;
  if (v1) {
    bto[b * PN + p1] = biB / buB;
    bti[b * PN + p1] = idB;
  }

  for (int off = 32; off; off >>= 1) cmax = fmaxf(cmax, __shfl_down(cmax, off));
  __shared__ float wm[4];
  if ((tid & 63) == 0) wm[tid >> 6] = cmax;
  __syncthreads();
  if (tid == 0)
    bmax[b * GXB + blockIdx.x] = f2key(fmaxf(fmaxf(wm[0], wm[1]), fmaxf(wm[2], wm[3])));
}

// ---------- K2: per-truth best prior (one block per (b, 4 truths)) ----------
__global__ void k_best_prior(const float* __restrict__ priors,
                             const float* __restrict__ targets,
                             float* __restrict__ bpo, int* __restrict__ bpi) {
  int bx = blockIdx.x;
  int b = bx >> 4;
  int t0 = (bx & 15) * TG;
  int tid = threadIdx.x;
  float ax1[TG], ay1[TG], ax2[TG], ay2[TG], area_a[TG];
#pragma unroll
  for (int i = 0; i < TG; i++) {
    const float* tg = &targets[((long)b * ON + t0 + i) * 15];
    ax1[i] = tg[0]; ay1[i] = tg[1]; ax2[i] = tg[2]; ay2[i] = tg[3];
    area_a[i] = (ax2[i] - ax1[i]) * (ay2[i] - ay1[i]);
  }
  float bi[TG], bu[TG]; int bp[TG];
#pragma unroll
  for (int i = 0; i < TG; i++) { bi[i] = -1.f; bu[i] = 1.f; bp[i] = 0x7FFFFFFF; }
  for (int p = tid; p < PN; p += 256) {
    float4 pr = reinterpret_cast<const float4*>(priors)[p];
    float px1 = pr.x - pr.z * 0.5f, py1 = pr.y - pr.w * 0.5f;
    float px2 = pr.x + pr.z * 0.5f, py2 = pr.y + pr.w * 0.5f;
    float area_b = (px2 - px1) * (py2 - py1);
#pragma unroll
    for (int i = 0; i < TG; i++) {
      float lx = fmaxf(ax1[i], px1), ly = fmaxf(ay1[i], py1);
      float rx = fminf(ax2[i], px2), ry = fminf(ay2[i], py2);
      float w = fmaxf(rx - lx, 0.f), h = fmaxf(ry - ly, 0.f);
      float inter = w * h;
      float uni = area_a[i] + area_b - inter;
      if (inter * bu[i] > bi[i] * uni) { bi[i] = inter; bu[i] = uni; bp[i] = p; }
    }
  }
#pragma unroll
  for (int off = 1; off < 64; off <<= 1) {
#pragma unroll
    for (int i = 0; i < TG; i++) {
      float oi = __shfl_xor(bi[i], off), ou = __shfl_xor(bu[i], off);
      int op = __shfl_xor(bp[i], off);
      float a = oi * bu[i], c = bi[i] * ou;
      if (a > c || (a == c && op < bp[i])) { bi[i] = oi; bu[i] = ou; bp[i] = op; }
    }
  }
  __shared__ float si[TG][4], su[TG][4];
  __shared__ int sp[TG][4];
  int w = tid >> 6;
  if ((tid & 63) == 0) {
#pragma unroll
    for (int i = 0; i < TG; i++) { si[i][w] = bi[i]; su[i][w] = bu[i]; sp[i][w] = bp[i]; }
  }
  __syncthreads();
  if (tid < TG) {
    float fi = si[tid][0], fu = su[tid][0]; int fp = sp[tid][0];
    for (int ww = 1; ww < 4; ww++) {
      float a = si[tid][ww] * fu, c = fi * su[tid][ww];
      if (a > c || (a == c && sp[tid][ww] < fp)) { fi = si[tid][ww]; fu = su[tid][ww]; fp = sp[tid][ww]; }
    }
    bpo[(long)b * ON + t0 + tid] = fi / fu;
    bpi[(long)b * ON + t0 + tid] = fp;
  }
}

// ---------- K3: parallel scatter (winner = last t per target) + conf-max reduce ----------
__global__ void k_scatter(const unsigned* __restrict__ bmax,
                          const float* __restrict__ bpo, const int* __restrict__ bpi,
                          float* __restrict__ bto, int* __restrict__ bti, Acc* acc) {
  int tid = threadIdx.x;
  if (blockIdx.x == 16) {  // conf-max reduction block
    unsigned mk = 0;
    for (int i = tid; i < NB_BT; i += 256) { unsigned v = bmax[i]; if (v > mk) mk = v; }
    for (int off = 1; off < 64; off <<= 1) {
      unsigned o = (unsigned)__shfl_xor((int)mk, off);
      if (o > mk) mk = o;
    }
    __shared__ unsigned wm[4];
    if ((tid & 63) == 0) wm[tid >> 6] = mk;
    __syncthreads();
    if (tid == 0) {
      unsigned m = wm[0];
      if (wm[1] > m) m = wm[1];
      if (wm[2] > m) m = wm[2];
      if (wm[3] > m) m = wm[3];
      acc->xmax_key = m;
    }
    return;
  }
  int row = blockIdx.x * 4 + (tid >> 6);
  int t = tid & 63;
  int q = bpi[row * ON + t];
  bool valid = bpo[row * ON + t] >= 0.2f;
  bool dupLater = false;
  for (int j = 0; j < 64; j++) {
    int ij = __shfl(q, j);
    if (j > t && ij == q) dupLater = true;
  }
  if (!dupLater) {
    bti[(long)row * PN + q] = t;
    if (valid) bto[(long)row * PN + q] = 2.0f;
  }
}

// ---------- K4: encode + smooth-l1 + loss_c + per-block partials ----------
__global__ void k_encode(const float* __restrict__ loc_data,
                         const float* __restrict__ conf_data,
                         const float* __restrict__ landm_data,
                         const float* __restrict__ priors,
                         const float* __restrict__ targets,
                         const float* __restrict__ bto, const int* __restrict__ bti,
                         float* __restrict__ lossc, unsigned char* __restrict__ posf,
                         const Acc* __restrict__ acc,
                         float* __restrict__ part_l, float* __restrict__ part_lm,
                         int* __restrict__ np_part, int* __restrict__ np1_part) {
  int b = blockIdx.y;
  int p = blockIdx.x * 256 + threadIdx.x;
  int bid = b * GX + blockIdx.x;
  __shared__ float tgs[ON * 15];
  for (int i = threadIdx.x; i < ON * 15; i += 256)
    tgs[i] = targets[(long)b * ON * 15 + i];
  __syncthreads();
  float sum_l = 0.f, sum_lm = 0.f;
  int cp = 0, cp1 = 0;
  if (p < PN) {
    int t = bti[b * PN + p];
    float ov = bto[b * PN + p];
    const float* tg = &tgs[t * 15];
    float label = tg[14];
    float conf = (ov < THRESH) ? 0.f : label;
    bool pos = (conf != 0.f);
    bool pos1 = (conf > 0.f);
    float4 pr = reinterpret_cast<const float4*>(priors)[p];
    if (pos) {
      float m0 = tg[0], m1 = tg[1], m2 = tg[2], m3 = tg[3];
      float g0 = ((m0 + m2) * 0.5f - pr.x) / (0.1f * pr.z);
      float g1 = ((m1 + m3) * 0.5f - pr.y) / (0.1f * pr.w);
      float g2 = logf((m2 - m0) / pr.z) / 0.2f;
      float g3 = logf((m3 - m1) / pr.w) / 0.2f;
      const float* ld = &loc_data[((long)b * PN + p) * 4];
      sum_l = sl1(ld[0] - g0) + sl1(ld[1] - g1) + sl1(ld[2] - g2) + sl1(ld[3] - g3);
      cp = 1;
    }
    if (pos1) {
      const float* lm = &landm_data[((long)b * PN + p) * 10];
      for (int i = 0; i < 5; i++) {
        float gx = (tg[4 + 2 * i] - pr.x) / (0.1f * pr.z);
        float gy = (tg[5 + 2 * i] - pr.y) / (0.1f * pr.w);
        sum_lm += sl1(lm[2 * i] - gx) + sl1(lm[2 * i + 1] - gy);
      }
      cp1 = 1;
    }
    float2 c2 = reinterpret_cast<const float2*>(conf_data)[(long)b * PN + p];
    float xmax = key2f(acc->xmax_key);
    float lse = logf(expf(c2.x - xmax) + expf(c2.y - xmax)) + xmax;
    lossc[b * PN + p] = lse - (pos ? c2.y : c2.x);
    posf[b * PN + p] = pos ? 1 : 0;
  }
  for (int off = 32; off; off >>= 1) {
    sum_l += __shfl_down(sum_l, off);
    sum_lm += __shfl_down(sum_lm, off);
    cp += __shfl_down(cp, off);
    cp1 += __shfl_down(cp1, off);
  }
  __shared__ float sl4[4], slm4[4];
  __shared__ int sp4[4], sp14[4];
  int w = threadIdx.x >> 6;
  if ((threadIdx.x & 63) == 0) { sl4[w] = sum_l; slm4[w] = sum_lm; sp4[w] = cp; sp14[w] = cp1; }
  __syncthreads();
  if (threadIdx.x == 0) {
    part_l[bid] = sl4[0] + sl4[1] + sl4[2] + sl4[3];
    part_lm[bid] = slm4[0] + slm4[1] + slm4[2] + slm4[3];
    np_part[bid] = sp4[0] + sp4[1] + sp4[2] + sp4[3];
    np1_part[bid] = sp14[0] + sp14[1] + sp14[2] + sp14[3];
  }
}

// ---------- K5: per-row radix select + fused CE sum ----------
__global__ void __launch_bounds__(1024) k_select_sum(const float* __restrict__ lossc,
                                                     const unsigned char* __restrict__ posf,
                                                     const int* __restrict__ np_part,
                                                     float* __restrict__ part_c) {
  int b = blockIdx.x;
  int tid = threadIdx.x;
  __shared__ unsigned hist[256], suf[256];
  __shared__ unsigned s_chosen, s_rem;
  __shared__ int s_np;
  const float* row = &lossc[(long)b * PN];
  const unsigned char* prow = &posf[(long)b * PN];

  if (tid == 0) s_np = 0;
  __syncthreads();
  if (tid < GX) atomicAdd(&s_np, np_part[b * GX + tid]);
  __syncthreads();
  int np = s_np;
  long k = (long)NEGPOS * np;
  if (k > PN - 1) k = PN - 1;

  unsigned T = 0xFFFFFFFFu, R = 0, C = 0;
  if (k > 0) {
    unsigned prefix = 0, remaining = (unsigned)k, lastC = 0;
    for (int pass = 0; pass < 4; pass++) {
      int shift = 24 - pass * 8;
      if (tid < 256) hist[tid] = 0;
      __syncthreads();
      unsigned hmask = (pass == 0) ? 0u : (0xFFFFFFFFu << (shift + 8));
      for (int p = tid; p < PN; p += 1024) {
        unsigned key = f2key(row[p]);
        if (((key ^ prefix) & hmask) == 0)
          atomicAdd(&hist[(key >> shift) & 255], 1u);
      }
      __syncthreads();
      if (tid < 256) suf[tid] = hist[tid];
      __syncthreads();
      for (int off = 1; off < 256; off <<= 1) {
        unsigned tv = 0;
        if (tid < 256 && tid + off < 256) tv = suf[tid + off];
        __syncthreads();
        if (tid < 256) suf[tid] += tv;
        __syncthreads();
      }
      if (tid < 256) {
        unsigned nextS = (tid < 255) ? suf[tid + 1] : 0;
        if (suf[tid] >= remaining && nextS < remaining) {
          s_chosen = (unsigned)tid;
          s_rem = remaining - nextS;
        }
      }
      __syncthreads();
      prefix |= s_chosen << shift;
      remaining = s_rem;
      if (pass == 3) lastC = hist[s_chosen];
      __syncthreads();
    }
    T = prefix; R = remaining; C = lastC;
  }

  float s = 0.f;
  bool fastTies = (R > 0 && C == R);
  for (int p = tid; p < PN; p += 1024) {
    bool pos = prow[p] != 0;
    float v = row[p];
    unsigned key = f2key(v);
    bool sel = pos || (R > 0 && (key > T || (key == T && fastTies)));
    if (sel) s += v;
  }
  if (R > 0 && C != R && tid < 64) {  // rare tie path
    unsigned running = 0;
    for (int base = 0; base < PN; base += 64) {
      int p = base + tid;
      bool tie = false, pos = false;
      float v = 0.f;
      if (p < PN) {
        v = row[p];
        tie = (f2key(v) == T);
        pos = prow[p] != 0;
      }
      unsigned long long m = __ballot(tie);
      if (tie) {
        unsigned rank = running + (unsigned)__popcll(m & ((1ull << tid) - 1));
        if (rank < R && !pos) s += v;
      }
      running += (unsigned)__popcll(m);
    }
  }
  for (int off = 32; off; off >>= 1) s += __shfl_down(s, off);
  __shared__ float ws[16];
  if ((tid & 63) == 0) ws[tid >> 6] = s;
  __syncthreads();
  if (tid == 0) {
    float tot = 0.f;
    for (int i = 0; i < 16; i++) tot += ws[i];
    part_c[b] = tot;
  }
}

// ---------- K6: reduce all partials, finalize three scalars ----------
__global__ void k_final(const float* __restrict__ part_l, const float* __restrict__ part_lm,
                        const float* __restrict__ part_c,
                        const int* __restrict__ np_part, const int* __restrict__ np1_part,
                        float* __restrict__ out) {
  float sl = 0.f, slm = 0.f, sc = 0.f;
  int np = 0, np1 = 0;
  for (int i = threadIdx.x; i < NBLK; i += 256) {
    sl += part_l[i]; slm += part_lm[i];
    np += np_part[i]; np1 += np1_part[i];
  }
  if (threadIdx.x < BN) sc = part_c[threadIdx.x];
  for (int off = 32; off; off >>= 1) {
    sl += __shfl_down(sl, off); slm += __shfl_down(slm, off); sc += __shfl_down(sc, off);
    np += __shfl_down(np, off); np1 += __shfl_down(np1, off);
  }
  __shared__ float a[4], bsh[4], c[4];
  __shared__ int d[4], e[4];
  int w = threadIdx.x >> 6;
  if ((threadIdx.x & 63) == 0) { a[w] = sl; bsh[w] = slm; c[w] = sc; d[w] = np; e[w] = np1; }
  __syncthreads();
  if (threadIdx.x == 0) {
    float N = fmaxf((float)(d[0] + d[1] + d[2] + d[3]), 1.f);
    float N1 = fmaxf((float)(e[0] + e[1] + e[2] + e[3]), 1.f);
    out[0] = (a[0] + a[1] + a[2] + a[3]) / N;
    out[1] = (c[0] + c[1] + c[2] + c[3]) / N;
    out[2] = (bsh[0] + bsh[1] + bsh[2] + bsh[3]) / N1;
  }
}

extern "C" void kernel_launch(void* const* d_in, const int* in_sizes, int n_in,
                              void* d_out, int out_size, void* d_ws, size_t ws_size,
                              hipStream_t stream) {
  const float* loc_data = (const float*)d_in[0];
  const float* conf_data = (const float*)d_in[1];
  const float* landm_data = (const float*)d_in[2];
  const float* priors = (const float*)d_in[3];
  const float* targets = (const float*)d_in[4];
  float* out = (float*)d_out;

  char* ws = (char*)d_ws;
  const size_t SZ = (size_t)BN * PN * 4;
  size_t off = 0;
  float* lossc = (float*)(ws + off); off += SZ;
  float* bto = (float*)(ws + off); off += SZ;
  int* bti = (int*)(ws + off); off += SZ;
  unsigned char* posf = (unsigned char*)(ws + off); off += (size_t)BN * PN;
  off = (off + 15) & ~(size_t)15;
  float* bpo = (float*)(ws + off); off += (size_t)BN * ON * 4;
  int* bpi = (int*)(ws + off); off += (size_t)BN * ON * 4;
  unsigned* bmax = (unsigned*)(ws + off); off += NB_BT * 4;
  float* part_l = (float*)(ws + off); off += NBLK * 4;
  float* part_lm = (float*)(ws + off); off += NBLK * 4;
  float* part_c = (float*)(ws + off); off += BN * 4;
  int* np_part = (int*)(ws + off); off += NBLK * 4;
  int* np1_part = (int*)(ws + off); off += NBLK * 4;
  Acc* acc = (Acc*)(ws + off); off += sizeof(Acc);

  dim3 gbt(GXB, BN);
  dim3 gbp(GX, BN);

  k_best_truth<<<gbt, 256, 0, stream>>>(priors, targets, conf_data, bto, bti, bmax);
  k_best_prior<<<BN * (ON / TG), 256, 0, stream>>>(priors, targets, bpo, bpi);
  k_scatter<<<17, 256, 0, stream>>>(bmax, bpo, bpi, bto, bti, acc);
  k_encode<<<gbp, 256, 0, stream>>>(loc_data, conf_data, landm_data, priors, targets,
                                    bto, bti, lossc, posf, acc,
                                    part_l, part_lm, np_part, np1_part);
  k_select_sum<<<BN, 1024, 0, stream>>>(lossc, posf, np_part, part_c);
  k_final<<<1, 256, 0, stream>>>(part_l, part_lm, part_c, np_part, np1_part, out);
}